// Round 16
// baseline (753.818 us; speedup 1.0000x reference)
//
#include <hip/hip_runtime.h>

typedef _Float16 h2 __attribute__((ext_vector_type(2)));
typedef _Float16 h8 __attribute__((ext_vector_type(8)));
typedef __fp16   g2 __attribute__((ext_vector_type(2)));
typedef __fp16   g8 __attribute__((ext_vector_type(8)));
typedef float    f32x4 __attribute__((ext_vector_type(4)));

#define TT 2048
#define HH 64
#define NL 8
#define NB 256
#define NBT 2                 // batch elements per block (interleaved chains)
#define NGRID (NB/NBT)        // 128 blocks
#define G  16                 // timesteps per sync interval
#define NCH (TT/G)            // 128 chunks per layer
#define NI  (NCH + NL)        // 136 intervals

union GU  { g8 v; g2 p[4]; h8 h; };   // LDS <-> MFMA frag bitcast

// buf: [bt][boundary idx 0..7 (= layer output l=idx+1? see below)][phase][slot 0..15][64 f16]
// idx wv is wave wv's OWN output boundary; wave wv>0's input boundary is idx wv-1.
// Within a slot row (128 B) the 16-B chunk c is stored at index c^(j&7).
#define BUFB(bt, idx, P) ((((bt)*8 + (idx))*2 + (P)) * 2048)
#define CH_OFF(j, c)  ((j)*128 + ((((c) ^ ((j)&7))) * 16))

// pre: [bt][layer][row16=nn][68]; element [nn][t*16+slot] = pre[slot][w-row t*16+nn]
#define PRE_ROW 68
#define PRE_LYR (16*PRE_ROW)
// xq: [bt][phase][slot][68 f32]
#define XQ_ROW 68
#define XQ_PH  (16*XQ_ROW)
#define XQ_BT  (2*XQ_PH)

__device__ __forceinline__ float tanh_fast(float v){
    float e = __expf(2.0f * v);
    float r = __builtin_amdgcn_rcpf(e + 1.0f);
    return fmaf(-2.0f, r, 1.0f);
}

__device__ __forceinline__ void gload_lds4(const float* g, float* l){
    __builtin_amdgcn_global_load_lds(
        (const __attribute__((address_space(1))) void*)g,
        (__attribute__((address_space(3))) void*)l, 4, 0, 0);
}

// ---------------------------------------------------------------------------
// R12 structure (best verified: flag sync + LDS-roundtrip MFMA recurrence),
// with TWO batch elements per block interleaved per step. The serial chain
// (write -> read -> MFMA -> select -> tanh, ~609 cyc measured R12) is hidden
// under the second batch's independent chain: both batches' reads issue
// together, then both MFMA groups, then both tails. Select-before-tanh:
// 1 tanh per batch per step. C-accumulated MFMA pairs (2-dep chain, half the
// accumulator registers of R12's C=0 form).
// Fragment conventions (R5/R8/R9-verified) unchanged.
// ---------------------------------------------------------------------------

#define XPROJ(bx0_, bx1_, preb) { \
    f32x4 x0 = {bs[0],bs[0],bs[0],bs[0]}, x1 = {bs[1],bs[1],bs[1],bs[1]}; \
    f32x4 x2 = {bs[2],bs[2],bs[2],bs[2]}, x3 = {bs[3],bs[3],bs[3],bs[3]}; \
    x0 = __builtin_amdgcn_mfma_f32_16x16x32_f16(bx0_.v, wihA[0][0].v, x0, 0, 0, 0); \
    x0 = __builtin_amdgcn_mfma_f32_16x16x32_f16(bx1_.v, wihA[0][1].v, x0, 0, 0, 0); \
    x1 = __builtin_amdgcn_mfma_f32_16x16x32_f16(bx0_.v, wihA[1][0].v, x1, 0, 0, 0); \
    x1 = __builtin_amdgcn_mfma_f32_16x16x32_f16(bx1_.v, wihA[1][1].v, x1, 0, 0, 0); \
    x2 = __builtin_amdgcn_mfma_f32_16x16x32_f16(bx0_.v, wihA[2][0].v, x2, 0, 0, 0); \
    x2 = __builtin_amdgcn_mfma_f32_16x16x32_f16(bx1_.v, wihA[2][1].v, x2, 0, 0, 0); \
    x3 = __builtin_amdgcn_mfma_f32_16x16x32_f16(bx0_.v, wihA[3][0].v, x3, 0, 0, 0); \
    x3 = __builtin_amdgcn_mfma_f32_16x16x32_f16(bx1_.v, wihA[3][1].v, x3, 0, 0, 0); \
    *(f32x4*)((preb) + nn*PRE_ROW + 0*16 + gq) = x0; \
    *(f32x4*)((preb) + nn*PRE_ROW + 1*16 + gq) = x1; \
    *(f32x4*)((preb) + nn*PRE_ROW + 2*16 + gq) = x2; \
    *(f32x4*)((preb) + nn*PRE_ROW + 3*16 + gq) = x3; \
}

#define XQREAD(bx0_, bx1_, xrp) { \
    f32x4 q0 = *(const f32x4*)((xrp) + g*8); \
    f32x4 q1 = *(const f32x4*)((xrp) + g*8 + 4); \
    f32x4 q2 = *(const f32x4*)((xrp) + 32 + g*8); \
    f32x4 q3 = *(const f32x4*)((xrp) + 36 + g*8); \
    bx0_.p[0] = __builtin_amdgcn_cvt_pkrtz(q0[0], q0[1]); \
    bx0_.p[1] = __builtin_amdgcn_cvt_pkrtz(q0[2], q0[3]); \
    bx0_.p[2] = __builtin_amdgcn_cvt_pkrtz(q1[0], q1[1]); \
    bx0_.p[3] = __builtin_amdgcn_cvt_pkrtz(q1[2], q1[3]); \
    bx1_.p[0] = __builtin_amdgcn_cvt_pkrtz(q2[0], q2[1]); \
    bx1_.p[1] = __builtin_amdgcn_cvt_pkrtz(q2[2], q2[3]); \
    bx1_.p[2] = __builtin_amdgcn_cvt_pkrtz(q3[0], q3[1]); \
    bx1_.p[3] = __builtin_amdgcn_cvt_pkrtz(q3[2], q3[3]); \
}

// one interleaved step: both batches' reads first, then MFMAs, then tails
#define DO_STEP2(jj, PW, mm_) { \
    GU hA0, hA1, hB0, hB1; \
    if ((jj) == 0){ hA0 = hpA0; hA1 = hpA1; hB0 = hpB0; hB1 = hpB1; } \
    else { \
        hA0.h = *(const h8*)(BB + BUFB(0, wv, PW) + CH_OFF((jj)-1, g)); \
        hA1.h = *(const h8*)(BB + BUFB(0, wv, PW) + CH_OFF((jj)-1, 4+g)); \
        hB0.h = *(const h8*)(BB + BUFB(1, wv, PW) + CH_OFF((jj)-1, g)); \
        hB1.h = *(const h8*)(BB + BUFB(1, wv, PW) + CH_OFF((jj)-1, 4+g)); \
    } \
    const float prA = preA[nn*PRE_ROW + g*16 + (jj)]; \
    const float prB = preB[nn*PRE_ROW + g*16 + (jj)]; \
    const f32x4 zz = {0.f, 0.f, 0.f, 0.f}; \
    f32x4 aA0 = __builtin_amdgcn_mfma_f32_16x16x32_f16(hA0.v, whhB[0][0].v, zz, 0, 0, 0); \
    f32x4 aA1 = __builtin_amdgcn_mfma_f32_16x16x32_f16(hA0.v, whhB[1][0].v, zz, 0, 0, 0); \
    f32x4 aA2 = __builtin_amdgcn_mfma_f32_16x16x32_f16(hA0.v, whhB[2][0].v, zz, 0, 0, 0); \
    f32x4 aA3 = __builtin_amdgcn_mfma_f32_16x16x32_f16(hA0.v, whhB[3][0].v, zz, 0, 0, 0); \
    f32x4 aB0 = __builtin_amdgcn_mfma_f32_16x16x32_f16(hB0.v, whhB[0][0].v, zz, 0, 0, 0); \
    f32x4 aB1 = __builtin_amdgcn_mfma_f32_16x16x32_f16(hB0.v, whhB[1][0].v, zz, 0, 0, 0); \
    f32x4 aB2 = __builtin_amdgcn_mfma_f32_16x16x32_f16(hB0.v, whhB[2][0].v, zz, 0, 0, 0); \
    f32x4 aB3 = __builtin_amdgcn_mfma_f32_16x16x32_f16(hB0.v, whhB[3][0].v, zz, 0, 0, 0); \
    aA0 = __builtin_amdgcn_mfma_f32_16x16x32_f16(hA1.v, whhB[0][1].v, aA0, 0, 0, 0); \
    aA1 = __builtin_amdgcn_mfma_f32_16x16x32_f16(hA1.v, whhB[1][1].v, aA1, 0, 0, 0); \
    aA2 = __builtin_amdgcn_mfma_f32_16x16x32_f16(hA1.v, whhB[2][1].v, aA2, 0, 0, 0); \
    aA3 = __builtin_amdgcn_mfma_f32_16x16x32_f16(hA1.v, whhB[3][1].v, aA3, 0, 0, 0); \
    aB0 = __builtin_amdgcn_mfma_f32_16x16x32_f16(hB1.v, whhB[0][1].v, aB0, 0, 0, 0); \
    aB1 = __builtin_amdgcn_mfma_f32_16x16x32_f16(hB1.v, whhB[1][1].v, aB1, 0, 0, 0); \
    aB2 = __builtin_amdgcn_mfma_f32_16x16x32_f16(hB1.v, whhB[2][1].v, aB2, 0, 0, 0); \
    aB3 = __builtin_amdgcn_mfma_f32_16x16x32_f16(hB1.v, whhB[3][1].v, aB3, 0, 0, 0); \
    const float tA01 = (g & 1) ? aA1[0] : aA0[0]; \
    const float tA23 = (g & 1) ? aA3[0] : aA2[0]; \
    const float hnA  = tanh_fast(((g & 2) ? tA23 : tA01) + prA); \
    const float tB01 = (g & 1) ? aB1[0] : aB0[0]; \
    const float tB23 = (g & 1) ? aB3[0] : aB2[0]; \
    const float hnB  = tanh_fast(((g & 2) ? tB23 : tB01) + prB); \
    *(_Float16*)(BB + BUFB(0, wv, PW) + (jj)*128 + (((lane>>3)^((jj)&7))*16) + (lane&7)*2) = (_Float16)hnA; \
    *(_Float16*)(BB + BUFB(1, wv, PW) + (jj)*128 + (((lane>>3)^((jj)&7))*16) + (lane&7)*2) = (_Float16)hnB; \
    if ((jj) == G-1){ \
        hpA0.h = *(const h8*)(BB + BUFB(0, wv, PW) + CH_OFF(G-1, g)); \
        hpA1.h = *(const h8*)(BB + BUFB(0, wv, PW) + CH_OFF(G-1, 4+g)); \
        hpB0.h = *(const h8*)(BB + BUFB(1, wv, PW) + CH_OFF(G-1, g)); \
        hpB1.h = *(const h8*)(BB + BUFB(1, wv, PW) + CH_OFF(G-1, 4+g)); \
        if ((mm_) - wv == NCH-1){ \
            hout[((size_t)wv*NB + b0)*HH + lane] = hnA; \
            hout[((size_t)wv*NB + b1)*HH + lane] = hnB; \
        } \
    } \
}

#define INTERVAL(MM, P) { \
    const int mm = (MM); \
    const bool act = (unsigned)(mm - wv) < (unsigned)NCH; \
    if (wv == 7 && mm >= 8){ \
        GU ya0, ya1, yb0, yb1; \
        ya0.h = *(const h8*)(BB + BUFB(0, 7, P) + CH_OFF(nn, g)); \
        ya1.h = *(const h8*)(BB + BUFB(0, 7, P) + CH_OFF(nn, 4+g)); \
        yb0.h = *(const h8*)(BB + BUFB(1, 7, P) + CH_OFF(nn, g)); \
        yb1.h = *(const h8*)(BB + BUFB(1, 7, P) + CH_OFF(nn, 4+g)); \
        f32x4 ayA = {0.f,0.f,0.f,0.f}, ayB = {0.f,0.f,0.f,0.f}; \
        ayA = __builtin_amdgcn_mfma_f32_16x16x32_f16(ya0.v, woutB[0].v, ayA, 0, 0, 0); \
        ayA = __builtin_amdgcn_mfma_f32_16x16x32_f16(ya1.v, woutB[1].v, ayA, 0, 0, 0); \
        ayB = __builtin_amdgcn_mfma_f32_16x16x32_f16(yb0.v, woutB[0].v, ayB, 0, 0, 0); \
        ayB = __builtin_amdgcn_mfma_f32_16x16x32_f16(yb1.v, woutB[1].v, ayB, 0, 0, 0); \
        if (nn == 0){ \
            f32x4 sA, sB; \
            sA[0]=ayA[0]+bout; sA[1]=ayA[1]+bout; sA[2]=ayA[2]+bout; sA[3]=ayA[3]+bout; \
            sB[0]=ayB[0]+bout; sB[1]=ayB[1]+bout; sB[2]=ayB[2]+bout; sB[3]=ayB[3]+bout; \
            *(f32x4*)(yout + (size_t)b0*TT + (size_t)(mm-8)*G + g*4) = sA; \
            *(f32x4*)(yout + (size_t)b1*TT + (size_t)(mm-8)*G + g*4) = sB; \
        } \
    } \
    if (act){ \
        if (wv > 0){ \
            while (((volatile int*)prodF)[wv] < mm) __builtin_amdgcn_s_sleep(1); \
            asm volatile("" ::: "memory"); \
        } \
        GU bxA0, bxA1, bxB0, bxB1; \
        if (wv == 0){ \
            asm volatile("s_waitcnt vmcnt(0)" ::: "memory"); \
            XQREAD(bxA0, bxA1, xqA + (mm&1)*XQ_PH + nn*XQ_ROW) \
            XQREAD(bxB0, bxB1, xqB + (mm&1)*XQ_PH + nn*XQ_ROW) \
            if (mm + 1 < NCH){ \
                const float* gx0 = x + ((size_t)b0*TT + (size_t)(mm+1)*G)*HH + lane; \
                const float* gx1 = x + ((size_t)b1*TT + (size_t)(mm+1)*G)*HH + lane; \
                float* lq0 = xqA + (1-(mm&1))*XQ_PH; \
                float* lq1 = xqB + (1-(mm&1))*XQ_PH; \
                _Pragma("unroll") \
                for (int j = 0; j < G; ++j){ \
                    gload_lds4(gx0 + j*HH, lq0 + j*XQ_ROW); \
                    gload_lds4(gx1 + j*HH, lq1 + j*XQ_ROW); \
                } \
            } \
        } else { \
            bxA0.h = *(const h8*)(BB + BUFB(0, wv-1, P) + CH_OFF(nn, g)); \
            bxA1.h = *(const h8*)(BB + BUFB(0, wv-1, P) + CH_OFF(nn, 4+g)); \
            bxB0.h = *(const h8*)(BB + BUFB(1, wv-1, P) + CH_OFF(nn, g)); \
            bxB1.h = *(const h8*)(BB + BUFB(1, wv-1, P) + CH_OFF(nn, 4+g)); \
        } \
        XPROJ(bxA0, bxA1, preA) \
        XPROJ(bxB0, bxB1, preB) \
        asm volatile("" ::: "memory"); \
        ((volatile int*)consF)[wv] = mm; \
        if (wv < 7){ \
            while (((volatile int*)consF)[wv+1] < mm-1) __builtin_amdgcn_s_sleep(1); \
            asm volatile("" ::: "memory"); \
        } \
        _Pragma("unroll") \
        for (int j = 0; j < G; ++j){ \
            DO_STEP2(j, 1-(P), mm) \
        } \
        asm volatile("" ::: "memory"); \
        ((volatile int*)prodF)[wv+1] = mm + 1; \
    } \
}

__attribute__((amdgpu_waves_per_eu(2, 2)))
__global__ void __launch_bounds__(512) rnn_kernel(
    const float* __restrict__ x,        // [B,T,64]
    const float* __restrict__ h_state,  // [8,B,64]
    const float* __restrict__ W_ih0,    // [64,64]
    const float* __restrict__ W_ih,     // [7,64,64]
    const float* __restrict__ W_hh,     // [8,64,64]
    const float* __restrict__ b_ih,     // [8,64]
    const float* __restrict__ b_hh,     // [8,64]
    const float* __restrict__ W_out,    // [1,64]
    const float* __restrict__ b_out,    // [1]
    float* __restrict__ out)            // y[256*2048] ++ h_final[8*256*64]
{
    __shared__ __attribute__((aligned(16))) _Float16 buf[NBT*8*2*16*64];   // 64 KB
    __shared__ __attribute__((aligned(16))) float pre[NBT*NL*PRE_LYR];     // 68 KB
    __shared__ __attribute__((aligned(16))) float xq[NBT*XQ_BT];           // 17 KB
    __shared__ int prodF[16];
    __shared__ int consF[16];
    char* BB = (char*)buf;
    const int tid  = threadIdx.x;
    const int wv   = tid >> 6;     // wave id == layer id
    const int lane = tid & 63;
    const int g    = lane >> 4;    // MFMA lane group
    const int nn   = lane & 15;    // MFMA row-in-tile / column
    const int gq   = g*4;
    const size_t b0 = (size_t)blockIdx.x * NBT;
    const size_t b1 = b0 + 1;
    float* preA = pre + (size_t)(0*NL + wv)*PRE_LYR;
    float* preB = pre + (size_t)(1*NL + wv)*PRE_LYR;
    float* xqA  = xq;
    float* xqB  = xq + XQ_BT;

    // ---- W_ih A-side and W_hh B-side fragments (R5/R9-verified maps) ----
    GU wihA[4][2], whhB[4][2];
    const float* Wi = (wv == 0) ? W_ih0 : (W_ih + (size_t)(wv-1)*HH*HH);
    const float* Wh = W_hh + (size_t)wv*HH*HH;
    #pragma unroll
    for (int t = 0; t < 4; ++t){
        #pragma unroll
        for (int kt = 0; kt < 2; ++kt){
            const float* pi = Wi + (size_t)(t*16 + nn)*HH + kt*32 + g*8;
            const float* ph = Wh + (size_t)(t*16 + nn)*HH + kt*32 + g*8;
            f32x4 i0 = *(const f32x4*)(pi), i1 = *(const f32x4*)(pi + 4);
            f32x4 h0 = *(const f32x4*)(ph), h1 = *(const f32x4*)(ph + 4);
            wihA[t][kt].p[0] = __builtin_amdgcn_cvt_pkrtz(i0[0], i0[1]);
            wihA[t][kt].p[1] = __builtin_amdgcn_cvt_pkrtz(i0[2], i0[3]);
            wihA[t][kt].p[2] = __builtin_amdgcn_cvt_pkrtz(i1[0], i1[1]);
            wihA[t][kt].p[3] = __builtin_amdgcn_cvt_pkrtz(i1[2], i1[3]);
            whhB[t][kt].p[0] = __builtin_amdgcn_cvt_pkrtz(h0[0], h0[1]);
            whhB[t][kt].p[1] = __builtin_amdgcn_cvt_pkrtz(h0[2], h0[3]);
            whhB[t][kt].p[2] = __builtin_amdgcn_cvt_pkrtz(h1[0], h1[1]);
            whhB[t][kt].p[3] = __builtin_amdgcn_cvt_pkrtz(h1[2], h1[3]);
        }
    }
    float bs[4];
    #pragma unroll
    for (int t = 0; t < 4; ++t)
        bs[t] = b_ih[wv*HH + t*16 + nn] + b_hh[wv*HH + t*16 + nn];
    float bout = b_out[0];

    GU woutB[2];
    if (wv == 7){
        #pragma unroll
        for (int kt = 0; kt < 2; ++kt)
            #pragma unroll
            for (int q = 0; q < 4; ++q)
                woutB[kt].p[q] = __builtin_amdgcn_cvt_pkrtz(
                    W_out[kt*32 + g*8 + q*2], W_out[kt*32 + g*8 + q*2 + 1]);
    }

    // ---- zero queues, init flags ----
    for (int i = tid; i < NBT*8*2*16*64; i += 512) buf[i] = (_Float16)0.f;
    if (tid < 16){
        prodF[tid] = 0;
        consF[tid] = tid - 2;
    }
    __syncthreads();
    // initial h_state (slot 15, phase 1-(wv&1)) for both batches
    *(_Float16*)(BB + BUFB(0, wv, 1-(wv&1)) + (G-1)*128 + (((lane>>3)^((G-1)&7))*16) + (lane&7)*2)
        = (_Float16)h_state[((size_t)wv*NB + b0)*HH + lane];
    *(_Float16*)(BB + BUFB(1, wv, 1-(wv&1)) + (G-1)*128 + (((lane>>3)^((G-1)&7))*16) + (lane&7)*2)
        = (_Float16)h_state[((size_t)wv*NB + b1)*HH + lane];
    // wave 0: preload x chunk 0 into xq phase 0 (both batches)
    if (wv == 0){
        const float* gx0 = x + (size_t)b0*TT*HH + lane;
        const float* gx1 = x + (size_t)b1*TT*HH + lane;
        #pragma unroll
        for (int j = 0; j < G; ++j){
            gload_lds4(gx0 + j*HH, xqA + j*XQ_ROW);
            gload_lds4(gx1 + j*HH, xqB + j*XQ_ROW);
        }
    }
    __syncthreads();

    // ---- prologue hp prefetch (slot 15 = h_state, same-wave order) ----
    GU hpA0, hpA1, hpB0, hpB1;
    hpA0.h = *(const h8*)(BB + BUFB(0, wv, 1-(wv&1)) + CH_OFF(G-1, g));
    hpA1.h = *(const h8*)(BB + BUFB(0, wv, 1-(wv&1)) + CH_OFF(G-1, 4+g));
    hpB0.h = *(const h8*)(BB + BUFB(1, wv, 1-(wv&1)) + CH_OFF(G-1, g));
    hpB1.h = *(const h8*)(BB + BUFB(1, wv, 1-(wv&1)) + CH_OFF(G-1, 4+g));

    float* yout = out;                    // [B*T]
    float* hout = out + (size_t)NB*TT;    // [8,B,64]

    for (int m2 = 0; m2 < NI; m2 += 2){
        INTERVAL(m2,     1)
        INTERVAL(m2 + 1, 0)
    }
    // no epilogue: interval NI-1 emits y for the final chunk (all 16 slots)
}

extern "C" void kernel_launch(void* const* d_in, const int* in_sizes, int n_in,
                              void* d_out, int out_size, void* d_ws, size_t ws_size,
                              hipStream_t stream) {
    (void)in_sizes; (void)n_in; (void)d_ws; (void)ws_size; (void)out_size;
    const float* x       = (const float*)d_in[0];
    const float* h_state = (const float*)d_in[1];
    const float* W_ih0   = (const float*)d_in[2];
    const float* W_ih    = (const float*)d_in[3];
    const float* W_hh    = (const float*)d_in[4];
    const float* b_ih    = (const float*)d_in[5];
    const float* b_hh    = (const float*)d_in[6];
    const float* W_out   = (const float*)d_in[7];
    const float* b_out   = (const float*)d_in[8];
    float* out = (float*)d_out;

    rnn_kernel<<<dim3(NGRID), dim3(512), 0, stream>>>(
        x, h_state, W_ih0, W_ih, W_hh, b_ih, b_hh, W_out, b_out, out);
}

// Round 18
// 433.936 us; speedup vs baseline: 1.7372x; 1.7372x over previous
//
#include <hip/hip_runtime.h>

typedef _Float16 h2 __attribute__((ext_vector_type(2)));
typedef _Float16 h8 __attribute__((ext_vector_type(8)));
typedef __fp16   g2 __attribute__((ext_vector_type(2)));
typedef __fp16   g8 __attribute__((ext_vector_type(8)));
typedef float    f32x4 __attribute__((ext_vector_type(4)));

#define TT 2048
#define HH 64
#define NL 8
#define NB 256
#define G  32            // timesteps per sync interval (R12 had 16)
#define NCH (TT/G)       // 64 chunks per layer
#define NI  (NCH + NL)   // 72 intervals

union GU { g8 v; g2 p[4]; h8 h; };    // LDS <-> MFMA frag bitcast

// buf: 8 boundaries (idx wv = wave wv's OWN output; wave wv>0 reads idx wv-1),
// 2 phases, 32 slots, 64 f16. 16-B chunk c of slot j stored at c^(j&7).
#define BUFB(idx, P) ((((idx)*2 + (P))) * 4096)
#define CH_OFF(j, c) ((j)*128 + ((((c) ^ ((j)&7))) * 16))

// pre: per layer [nn=16][t=4][32 slots]; t-stride 36 (9 chunks odd),
// nn-stride 148 (37 chunks odd) -> conflict-free b128 spill/readback.
#define PRP 36
#define NNS 148
#define PRE_L (16*NNS)

// xq: [phase][slot 0..31][68 f32] (row stride 17 chunks, odd)
#define XQ_ROW 68
#define XQ_PH  (32*XQ_ROW)

__device__ __forceinline__ float tanh_fast(float v){
    float e = __expf(2.0f * v);
    float r = __builtin_amdgcn_rcpf(e + 1.0f);
    return fmaf(-2.0f, r, 1.0f);
}

__device__ __forceinline__ void gload_lds4(const float* g, float* l){
    __builtin_amdgcn_global_load_lds(
        (const __attribute__((address_space(1))) void*)g,
        (__attribute__((address_space(3))) void*)l, 4, 0, 0);
}

// ---------------------------------------------------------------------------
// R12 structure (best verified: flag sync + LDS-roundtrip MFMA recurrence,
// 552 us rocprof) with G=32: halves the count of per-interval overheads
// (x-proj head ~1100 cyc, measured via the G=8/G=16 two-point fit).
// x comes via the R15-proven global_load_lds xq queue (boundary 0 removed).
// Step loop, fragment maps, flag protocol byte-identical to R12.
// (R17 fix: P threaded through YPROJ as an explicit macro parameter —
//  nested macro bodies don't see the enclosing macro's parameters.)
// ---------------------------------------------------------------------------

#define XPROJ(bx0_, bx1_, off16) { \
    f32x4 x0 = {bs[0],bs[0],bs[0],bs[0]}, x1 = {bs[1],bs[1],bs[1],bs[1]}; \
    f32x4 x2 = {bs[2],bs[2],bs[2],bs[2]}, x3 = {bs[3],bs[3],bs[3],bs[3]}; \
    x0 = __builtin_amdgcn_mfma_f32_16x16x32_f16(bx0_.v, wihA[0][0].v, x0, 0, 0, 0); \
    x0 = __builtin_amdgcn_mfma_f32_16x16x32_f16(bx1_.v, wihA[0][1].v, x0, 0, 0, 0); \
    x1 = __builtin_amdgcn_mfma_f32_16x16x32_f16(bx0_.v, wihA[1][0].v, x1, 0, 0, 0); \
    x1 = __builtin_amdgcn_mfma_f32_16x16x32_f16(bx1_.v, wihA[1][1].v, x1, 0, 0, 0); \
    x2 = __builtin_amdgcn_mfma_f32_16x16x32_f16(bx0_.v, wihA[2][0].v, x2, 0, 0, 0); \
    x2 = __builtin_amdgcn_mfma_f32_16x16x32_f16(bx1_.v, wihA[2][1].v, x2, 0, 0, 0); \
    x3 = __builtin_amdgcn_mfma_f32_16x16x32_f16(bx0_.v, wihA[3][0].v, x3, 0, 0, 0); \
    x3 = __builtin_amdgcn_mfma_f32_16x16x32_f16(bx1_.v, wihA[3][1].v, x3, 0, 0, 0); \
    *(f32x4*)(preW + nn*NNS + 0*PRP + (off16) + gq) = x0; \
    *(f32x4*)(preW + nn*NNS + 1*PRP + (off16) + gq) = x1; \
    *(f32x4*)(preW + nn*NNS + 2*PRP + (off16) + gq) = x2; \
    *(f32x4*)(preW + nn*NNS + 3*PRP + (off16) + gq) = x3; \
}

#define XQREAD(bx0_, bx1_, xrp) { \
    f32x4 q0 = *(const f32x4*)((xrp) + g*8); \
    f32x4 q1 = *(const f32x4*)((xrp) + g*8 + 4); \
    f32x4 q2 = *(const f32x4*)((xrp) + 32 + g*8); \
    f32x4 q3 = *(const f32x4*)((xrp) + 36 + g*8); \
    bx0_.p[0] = __builtin_amdgcn_cvt_pkrtz(q0[0], q0[1]); \
    bx0_.p[1] = __builtin_amdgcn_cvt_pkrtz(q0[2], q0[3]); \
    bx0_.p[2] = __builtin_amdgcn_cvt_pkrtz(q1[0], q1[1]); \
    bx0_.p[3] = __builtin_amdgcn_cvt_pkrtz(q1[2], q1[3]); \
    bx1_.p[0] = __builtin_amdgcn_cvt_pkrtz(q2[0], q2[1]); \
    bx1_.p[1] = __builtin_amdgcn_cvt_pkrtz(q2[2], q2[3]); \
    bx1_.p[2] = __builtin_amdgcn_cvt_pkrtz(q3[0], q3[1]); \
    bx1_.p[3] = __builtin_amdgcn_cvt_pkrtz(q3[2], q3[3]); \
}

#define YPROJ(slotrow, ofs, PP) { \
    GU ya0, ya1; \
    ya0.h = *(const h8*)(BB + BUFB(7, PP) + CH_OFF((slotrow), g)); \
    ya1.h = *(const h8*)(BB + BUFB(7, PP) + CH_OFF((slotrow), 4+g)); \
    f32x4 ay = {0.f, 0.f, 0.f, 0.f}; \
    ay = __builtin_amdgcn_mfma_f32_16x16x32_f16(ya0.v, woutB[0].v, ay, 0, 0, 0); \
    ay = __builtin_amdgcn_mfma_f32_16x16x32_f16(ya1.v, woutB[1].v, ay, 0, 0, 0); \
    if (nn == 0){ \
        f32x4 st; \
        st[0] = ay[0] + bout; st[1] = ay[1] + bout; \
        st[2] = ay[2] + bout; st[3] = ay[3] + bout; \
        *(f32x4*)(yout + (size_t)b*TT + (size_t)(mm-8)*G + (ofs) + g*4) = st; \
    } \
}

#define INTERVAL(MM, P) { \
    const int mm = (MM); \
    const bool act = (unsigned)(mm - wv) < (unsigned)NCH; \
    if (wv == 7 && mm >= 8){ \
        YPROJ(nn, 0, P) \
        YPROJ(16+nn, 16, P) \
    } \
    if (act){ \
        if (wv > 0){ \
            while (((volatile int*)prodF)[wv] < mm) __builtin_amdgcn_s_sleep(1); \
            asm volatile("" ::: "memory"); \
        } \
        /* ---- x-projection inputs, both 16-slot halves ---- */ \
        GU bxA0, bxA1, bxB0, bxB1; \
        if (wv == 0){ \
            asm volatile("s_waitcnt vmcnt(0)" ::: "memory"); \
            XQREAD(bxA0, bxA1, xq + (mm&1)*XQ_PH + nn*XQ_ROW) \
            XQREAD(bxB0, bxB1, xq + (mm&1)*XQ_PH + (16+nn)*XQ_ROW) \
            if (mm + 1 < NCH){ \
                const float* gx = x + ((size_t)b*TT + (size_t)(mm+1)*G)*HH + lane; \
                float* lq = xq + (1-(mm&1))*XQ_PH; \
                _Pragma("unroll") \
                for (int j = 0; j < G; ++j) \
                    gload_lds4(gx + j*HH, lq + j*XQ_ROW); \
            } \
        } else { \
            bxA0.h = *(const h8*)(BB + BUFB(wv-1, P) + CH_OFF(nn, g)); \
            bxA1.h = *(const h8*)(BB + BUFB(wv-1, P) + CH_OFF(nn, 4+g)); \
            bxB0.h = *(const h8*)(BB + BUFB(wv-1, P) + CH_OFF(16+nn, g)); \
            bxB1.h = *(const h8*)(BB + BUFB(wv-1, P) + CH_OFF(16+nn, 4+g)); \
        } \
        XPROJ(bxA0, bxA1, 0) \
        XPROJ(bxB0, bxB1, 16) \
        asm volatile("" ::: "memory"); \
        ((volatile int*)consF)[wv] = mm; \
        if (wv < 7){ \
            while (((volatile int*)consF)[wv+1] < mm-1) __builtin_amdgcn_s_sleep(1); \
            asm volatile("" ::: "memory"); \
        } \
        /* readback quads: half0 upfront; each quad reloads with half1 data */ \
        /* right after its last half0 use (prv[q] serves j in {q*4.., 16+q*4..}) */ \
        const float* pb = preW + nn*NNS + g*PRP; \
        f32x4 prv0 = *(const f32x4*)(pb);      f32x4 prv1 = *(const f32x4*)(pb + 4); \
        f32x4 prv2 = *(const f32x4*)(pb + 8);  f32x4 prv3 = *(const f32x4*)(pb + 12); \
        /* ---- 32 serial steps (R12 chain, verbatim) ---- */ \
        _Pragma("unroll") \
        for (int j = 0; j < G; ++j){ \
            GU hA0, hA1; \
            if (j == 0){ hA0 = hp0; hA1 = hp1; } \
            else { \
                hA0.h = *(const h8*)(BB + BUFB(wv, 1-(P)) + CH_OFF(j-1, g)); \
                hA1.h = *(const h8*)(BB + BUFB(wv, 1-(P)) + CH_OFF(j-1, 4+g)); \
            } \
            const f32x4 zz = {0.f, 0.f, 0.f, 0.f}; \
            f32x4 a00 = __builtin_amdgcn_mfma_f32_16x16x32_f16(hA0.v, whhB[0][0].v, zz, 0, 0, 0); \
            f32x4 a01 = __builtin_amdgcn_mfma_f32_16x16x32_f16(hA1.v, whhB[0][1].v, zz, 0, 0, 0); \
            f32x4 a10 = __builtin_amdgcn_mfma_f32_16x16x32_f16(hA0.v, whhB[1][0].v, zz, 0, 0, 0); \
            f32x4 a11 = __builtin_amdgcn_mfma_f32_16x16x32_f16(hA1.v, whhB[1][1].v, zz, 0, 0, 0); \
            f32x4 a20 = __builtin_amdgcn_mfma_f32_16x16x32_f16(hA0.v, whhB[2][0].v, zz, 0, 0, 0); \
            f32x4 a21 = __builtin_amdgcn_mfma_f32_16x16x32_f16(hA1.v, whhB[2][1].v, zz, 0, 0, 0); \
            f32x4 a30 = __builtin_amdgcn_mfma_f32_16x16x32_f16(hA0.v, whhB[3][0].v, zz, 0, 0, 0); \
            f32x4 a31 = __builtin_amdgcn_mfma_f32_16x16x32_f16(hA1.v, whhB[3][1].v, zz, 0, 0, 0); \
            const float s0 = a00[0] + a01[0], s1 = a10[0] + a11[0]; \
            const float s2 = a20[0] + a21[0], s3 = a30[0] + a31[0]; \
            const float pa = (g & 2) ? ((g & 1) ? s3 : s2) : ((g & 1) ? s1 : s0); \
            float prj; \
            { const int q = (j >> 2) & 3; \
              prj = (q == 0) ? prv0[j&3] : (q == 1) ? prv1[j&3] \
                  : (q == 2) ? prv2[j&3] : prv3[j&3]; } \
            const float hn = tanh_fast(pa + prj); \
            *(_Float16*)(BB + BUFB(wv, 1-(P)) + j*128 + (((lane>>3)^(j&7))*16) + (lane&7)*2) = (_Float16)hn; \
            if (j == 4)  prv0 = *(const f32x4*)(pb + 16); \
            if (j == 8)  prv1 = *(const f32x4*)(pb + 20); \
            if (j == 12) prv2 = *(const f32x4*)(pb + 24); \
            if (j == 16) prv3 = *(const f32x4*)(pb + 28); \
            if (j == G-1){ \
                hp0.h = *(const h8*)(BB + BUFB(wv, 1-(P)) + CH_OFF(G-1, g)); \
                hp1.h = *(const h8*)(BB + BUFB(wv, 1-(P)) + CH_OFF(G-1, 4+g)); \
                if (mm - wv == NCH-1) \
                    hout[((size_t)wv*NB + b)*HH + lane] = hn; \
            } \
        } \
        asm volatile("" ::: "memory"); \
        ((volatile int*)prodF)[wv+1] = mm + 1; \
    } \
}

__attribute__((amdgpu_waves_per_eu(2, 2)))
__global__ void __launch_bounds__(512) rnn_kernel(
    const float* __restrict__ x,        // [B,T,64]
    const float* __restrict__ h_state,  // [8,B,64]
    const float* __restrict__ W_ih0,    // [64,64]
    const float* __restrict__ W_ih,     // [7,64,64]
    const float* __restrict__ W_hh,     // [8,64,64]
    const float* __restrict__ b_ih,     // [8,64]
    const float* __restrict__ b_hh,     // [8,64]
    const float* __restrict__ W_out,    // [1,64]
    const float* __restrict__ b_out,    // [1]
    float* __restrict__ out)            // y[256*2048] ++ h_final[8*256*64]
{
    __shared__ __attribute__((aligned(16))) _Float16 buf[8*2*G*HH];   // 64 KB
    __shared__ __attribute__((aligned(16))) float pre[NL*PRE_L];      // 74 KB
    __shared__ __attribute__((aligned(16))) float xq[2*XQ_PH];        // 17 KB
    __shared__ int prodF[16];
    __shared__ int consF[16];
    char* BB = (char*)buf;
    const int tid  = threadIdx.x;
    const int wv   = tid >> 6;     // wave id == layer id
    const int lane = tid & 63;
    const int g    = lane >> 4;    // MFMA lane group
    const int nn   = lane & 15;    // MFMA row-in-tile / column
    const int gq   = g*4;
    const size_t b = blockIdx.x;
    float* preW = pre + (size_t)wv*PRE_L;

    // ---- W_ih A-side / W_hh B-side fragments (R5/R9-verified maps) ----
    GU wihA[4][2], whhB[4][2];
    const float* Wi = (wv == 0) ? W_ih0 : (W_ih + (size_t)(wv-1)*HH*HH);
    const float* Wh = W_hh + (size_t)wv*HH*HH;
    #pragma unroll
    for (int t = 0; t < 4; ++t){
        #pragma unroll
        for (int kt = 0; kt < 2; ++kt){
            const float* pi = Wi + (size_t)(t*16 + nn)*HH + kt*32 + g*8;
            const float* ph = Wh + (size_t)(t*16 + nn)*HH + kt*32 + g*8;
            f32x4 i0 = *(const f32x4*)(pi), i1 = *(const f32x4*)(pi + 4);
            f32x4 h0 = *(const f32x4*)(ph), h1 = *(const f32x4*)(ph + 4);
            wihA[t][kt].p[0] = __builtin_amdgcn_cvt_pkrtz(i0[0], i0[1]);
            wihA[t][kt].p[1] = __builtin_amdgcn_cvt_pkrtz(i0[2], i0[3]);
            wihA[t][kt].p[2] = __builtin_amdgcn_cvt_pkrtz(i1[0], i1[1]);
            wihA[t][kt].p[3] = __builtin_amdgcn_cvt_pkrtz(i1[2], i1[3]);
            whhB[t][kt].p[0] = __builtin_amdgcn_cvt_pkrtz(h0[0], h0[1]);
            whhB[t][kt].p[1] = __builtin_amdgcn_cvt_pkrtz(h0[2], h0[3]);
            whhB[t][kt].p[2] = __builtin_amdgcn_cvt_pkrtz(h1[0], h1[1]);
            whhB[t][kt].p[3] = __builtin_amdgcn_cvt_pkrtz(h1[2], h1[3]);
        }
    }
    float bs[4];
    #pragma unroll
    for (int t = 0; t < 4; ++t)
        bs[t] = b_ih[wv*HH + t*16 + nn] + b_hh[wv*HH + t*16 + nn];
    float bout = b_out[0];

    GU woutB[2];
    if (wv == 7){
        #pragma unroll
        for (int kt = 0; kt < 2; ++kt)
            #pragma unroll
            for (int q = 0; q < 4; ++q)
                woutB[kt].p[q] = __builtin_amdgcn_cvt_pkrtz(
                    W_out[kt*32 + g*8 + q*2], W_out[kt*32 + g*8 + q*2 + 1]);
    }

    // ---- zero boundary queues, init flags ----
    for (int i = tid; i < 8*2*G*HH; i += 512) buf[i] = (_Float16)0.f;
    if (tid < 16){
        prodF[tid] = 0;
        consF[tid] = tid - 2;
    }
    __syncthreads();
    // initial h_state -> own boundary, slot 31, phase 1-(wv&1)
    *(_Float16*)(BB + BUFB(wv, 1-(wv&1)) + (G-1)*128 + (((lane>>3)^((G-1)&7))*16) + (lane&7)*2)
        = (_Float16)h_state[((size_t)wv*NB + b)*HH + lane];
    // wave 0: preload x chunk 0 into xq phase 0
    if (wv == 0){
        const float* gx = x + (size_t)b*TT*HH + lane;
        #pragma unroll
        for (int j = 0; j < G; ++j)
            gload_lds4(gx + j*HH, xq + j*XQ_ROW);
    }
    __syncthreads();

    // ---- prologue hp prefetch (slot 31 = h_state; same-wave DS order) ----
    GU hp0, hp1;
    hp0.h = *(const h8*)(BB + BUFB(wv, 1-(wv&1)) + CH_OFF(G-1, g));
    hp1.h = *(const h8*)(BB + BUFB(wv, 1-(wv&1)) + CH_OFF(G-1, 4+g));

    float* yout = out;                    // [B*T]
    float* hout = out + (size_t)NB*TT;    // [8,B,64]

    for (int m2 = 0; m2 < NI; m2 += 2){
        INTERVAL(m2,     1)
        INTERVAL(m2 + 1, 0)
    }
    // no epilogue: interval NI-1 emits y for the final chunk (all 32 slots)
}

extern "C" void kernel_launch(void* const* d_in, const int* in_sizes, int n_in,
                              void* d_out, int out_size, void* d_ws, size_t ws_size,
                              hipStream_t stream) {
    (void)in_sizes; (void)n_in; (void)d_ws; (void)ws_size; (void)out_size;
    const float* x       = (const float*)d_in[0];
    const float* h_state = (const float*)d_in[1];
    const float* W_ih0   = (const float*)d_in[2];
    const float* W_ih    = (const float*)d_in[3];
    const float* W_hh    = (const float*)d_in[4];
    const float* b_ih    = (const float*)d_in[5];
    const float* b_hh    = (const float*)d_in[6];
    const float* W_out   = (const float*)d_in[7];
    const float* b_out   = (const float*)d_in[8];
    float* out = (float*)d_out;

    rnn_kernel<<<dim3(NB), dim3(512), 0, stream>>>(
        x, h_state, W_ih0, W_ih, W_hh, b_ih, b_hh, W_out, b_out, out);
}